// Round 3
// baseline (2006.725 us; speedup 1.0000x reference)
//
#include <hip/hip_runtime.h>
#include <hip/hip_bf16.h>

// 4 stacked LSTM layers (512->64, 64->64, 64->6, 6->6) + FC(6->6).
// B=64, T=1024, M = B*T = 65536.
//
// R8: one-barrier fused pipeline. R7's step was 3419 cy (2 barriers + 2 LDS
//     round-trips + serial phase C with idle waves); R6 proved 1062 cy/step
//     for the identical per-wave shape with ONE barrier. So: eliminate the
//     h-exchange phase entirely — every consumer wave redundantly recomputes
//     the producer layer's nonlinearity from the gate pre-activations in LDS
//     (same f32 values, same ops => bit-identical h), keeping private
//     (h,c) state copies. Step per wave: read gates[prv] -> nonlin -> pack
//     -> readlane-dot -> write gates[cur] -> lgkm -> barrier. 10 waves:
//     0-3 L1 gate-split, 4-7 L2 gate-split (rebuild h1 AND h2), 8 L3 (rebuild
//     h2, in-register broadcast, bpermute gate exchange), 9 L4+FC (h3 via a
//     6-float LDS write riding the same barrier).

#define B_SZ 64
#define T_SZ 1024
#define M_SZ (B_SZ * T_SZ)

typedef _Float16 h2   __attribute__((ext_vector_type(2)));
typedef _Float16 h8   __attribute__((ext_vector_type(8)));
typedef float    f32x4 __attribute__((ext_vector_type(4)));

__device__ __forceinline__ float sigm_f(float x) {
    return 1.0f / (1.0f + __expf(-x));
}
__device__ __forceinline__ float tanh_f(float x) {
    return 2.0f / (1.0f + __expf(-2.0f * x)) - 1.0f;
}

__device__ __forceinline__ float fdot2f(h2 a, h2 b, float c) {
#if __has_builtin(__builtin_amdgcn_fdot2)
    return __builtin_amdgcn_fdot2(a, b, c, false);
#else
    return c + (float)a.x * (float)b.x + (float)a.y * (float)b.y;
#endif
}

__device__ __forceinline__ unsigned pack_h2(float a, float b) {
    h2 p; p.x = (_Float16)a; p.y = (_Float16)b;
    return __builtin_bit_cast(unsigned, p);
}
__device__ __forceinline__ h2 as_h2(unsigned x) { return __builtin_bit_cast(h2, x); }
__device__ __forceinline__ float as_f(unsigned x) { return __builtin_bit_cast(float, x); }
__device__ __forceinline__ float as_f(int x) { return __builtin_bit_cast(float, x); }

// even lane 2i ends with {h[2i], h[2i+1]} packed as 2xf16
__device__ __forceinline__ int pack_pair(float h) {
    const _Float16 hf = (_Float16)h;
    const int hb = (int)__builtin_bit_cast(unsigned short, hf);
    const int nb = __builtin_amdgcn_update_dpp(0, hb, 0xB1, 0xF, 0xF, true);
    return hb | (nb << 16);
}

__device__ __forceinline__ void lstm_cell(float p0, float p1, float p2, float p3,
                                          float& c, float& h) {
    const float iv = sigm_f(p0);
    const float fv = sigm_f(p1);
    const float gv = tanh_f(p2);
    const float ov = sigm_f(p3);
    c = fv * c + iv * gv;
    h = ov * tanh_f(c);
}

// ---------------- fp32 -> f16 converter (for W_ih weights) ------------------
__global__ __launch_bounds__(256) void f32_to_f16(const float* __restrict__ src,
                                                  _Float16* __restrict__ dst, int n) {
    const int i = blockIdx.x * 256 + threadIdx.x;
    if (i < n) dst[i] = (_Float16)src[i];
}

// ---------------- MFMA input-projection GEMM (layer 1 only) -----------------
template <int K>
__global__ __launch_bounds__(256) void gemm_mfma(const float* __restrict__ X,
                                                 const _Float16* __restrict__ W16,
                                                 const float* __restrict__ bias,
                                                 float* __restrict__ out) {
    const int m0   = blockIdx.x * 64;
    const int tid  = threadIdx.x;
    const int wv   = tid >> 6;
    const int lane = tid & 63;
    const int lh   = lane & 15;
    const int quad = lane >> 4;
    const int n0   = wv * 64;

    __shared__ __align__(16) _Float16 Als[64 * 32];

    f32x4 acc[4][4];
#pragma unroll
    for (int nt = 0; nt < 4; ++nt) {
        const float bg = bias[n0 + nt * 16 + lh];
#pragma unroll
        for (int mt = 0; mt < 4; ++mt) {
            acc[mt][nt].x = bg; acc[mt][nt].y = bg;
            acc[mt][nt].z = bg; acc[mt][nt].w = bg;
        }
    }

    const int srow = tid >> 2;
    const int sk8  = tid & 3;
    const int sdst = srow * 32 + ((sk8 ^ (srow & 3)) * 8);

    for (int k0 = 0; k0 < K; k0 += 32) {
        const float* xr = X + (size_t)(m0 + srow) * K + k0 + sk8 * 8;
        const float4 a4 = ((const float4*)xr)[0];
        const float4 b4 = ((const float4*)xr)[1];
        h8 bfrag[4];
#pragma unroll
        for (int nt = 0; nt < 4; ++nt) {
            bfrag[nt] = *(const h8*)&W16[(size_t)(n0 + nt * 16 + lh) * K + k0 + quad * 8];
        }
        h8 hv;
        hv[0] = (_Float16)a4.x; hv[1] = (_Float16)a4.y;
        hv[2] = (_Float16)a4.z; hv[3] = (_Float16)a4.w;
        hv[4] = (_Float16)b4.x; hv[5] = (_Float16)b4.y;
        hv[6] = (_Float16)b4.z; hv[7] = (_Float16)b4.w;

        __syncthreads();
        *(h8*)&Als[sdst] = hv;
        __syncthreads();

        h8 afrag[4];
#pragma unroll
        for (int mt = 0; mt < 4; ++mt) {
            const int row = mt * 16 + lh;
            afrag[mt] = *(const h8*)&Als[row * 32 + ((quad ^ (row & 3)) * 8)];
        }
#pragma unroll
        for (int mt = 0; mt < 4; ++mt)
#pragma unroll
            for (int nt = 0; nt < 4; ++nt)
                acc[mt][nt] = __builtin_amdgcn_mfma_f32_16x16x32_f16(
                    afrag[mt], bfrag[nt], acc[mt][nt], 0, 0, 0);
    }

#pragma unroll
    for (int mt = 0; mt < 4; ++mt)
#pragma unroll
        for (int nt = 0; nt < 4; ++nt)
#pragma unroll
            for (int r = 0; r < 4; ++r)
                out[(size_t)(m0 + mt * 16 + quad * 4 + r) * 256 + n0 + nt * 16 + lh] =
                    acc[mt][nt][r];
}

// ---------------- fused pipelined scan: L1 + L2 + L3 + L4 + FC --------------
// One block per batch, 10 waves, ONE barrier per step.
// At step s: L1 writes gates(h1[s]); L2 writes gates(h2[s-1]); wave 8 writes
// h3[s-2]; wave 9 computes h4[s-3] and writes out[s-4]. s = 0 .. T+3.
__global__ __launch_bounds__(640, 1) void lstm_fused(
        const float* __restrict__ xg1,    // [B,T,256]  (b1_0 already added)
        const float* __restrict__ whh1,   // [256][64]
        const float* __restrict__ wih2,   // [256][64]
        const float* __restrict__ whh2,   // [256][64]
        const float* __restrict__ b2v,    // [256]
        const float* __restrict__ wih3,   // [24][64]
        const float* __restrict__ whh3,   // [24][6]
        const float* __restrict__ b3v,    // [24]
        const float* __restrict__ wih4,   // [24][6]
        const float* __restrict__ whh4,   // [24][6]
        const float* __restrict__ b4v,    // [24]
        const float* __restrict__ fcw,    // [6][6]
        const float* __restrict__ fcb,    // [6]
        float* __restrict__ out) {        // [B,T,6]
    const int b   = blockIdx.x;
    const int tid = threadIdx.x;
    const int wid = tid >> 6;
    const int u   = tid & 63;

    __shared__ __align__(16) float g1ls[2][4][64];
    __shared__ __align__(16) float g2ls[2][4][64];
    __shared__ __align__(16) float h3f[2][8];

    // role-overlaid register file
    unsigned wr[64];
    float    wx[8];
#pragma unroll
    for (int i = 0; i < 8; ++i) wx[i] = 0.0f;

    const float* xgb = xg1 + (size_t)b * T_SZ * 256 + (wid & 3) * 64 + u;
    float xv0 = 0.0f, xv1 = 0.0f;
    float hP = 0.0f, cP = 0.0f;      // L1: (h1,c1); L2: (h1,c1) copy; W8: (h2,c2)
    float hQ = 0.0f, cQ = 0.0f;      // L2: (h2,c2) copy; W8: (h3,c3); W9: (h4,c4)
    const int uu4 = 4 * (u % 6);

    if (wid < 4) {
        const float* wrow = whh1 + (size_t)(wid * 64 + u) * 64;
#pragma unroll
        for (int k2 = 0; k2 < 32; ++k2) wr[k2] = pack_h2(wrow[2 * k2], wrow[2 * k2 + 1]);
        xv0 = xgb[0];
        xv1 = xgb[256];
    } else if (wid < 8) {
        const int g = wid - 4;
        const float* wi = wih2 + (size_t)(g * 64 + u) * 64;
        const float* wh = whh2 + (size_t)(g * 64 + u) * 64;
#pragma unroll
        for (int k2 = 0; k2 < 32; ++k2) {
            wr[k2]      = pack_h2(wi[2 * k2], wi[2 * k2 + 1]);
            wr[32 + k2] = pack_h2(wh[2 * k2], wh[2 * k2 + 1]);
        }
        wx[0] = b2v[g * 64 + u];
    } else if (wid == 8) {
        const int q = (u < 24) ? u : 23;
#pragma unroll
        for (int j = 0; j < 64; ++j)
            wr[j] = __builtin_bit_cast(unsigned, wih3[(size_t)q * 64 + j]);
#pragma unroll
        for (int k = 0; k < 6; ++k) wx[k] = whh3[q * 6 + k];
        wx[6] = b3v[q];
    } else {
        const int q4 = (u < 6) ? u : 0;
        const int qf = (u >= 6 && u < 12) ? (u - 6) : 0;
#pragma unroll
        for (int g = 0; g < 4; ++g) {
#pragma unroll
            for (int k = 0; k < 6; ++k) {
                wr[g * 12 + k]     = __builtin_bit_cast(unsigned, wih4[(g * 6 + q4) * 6 + k]);
                wr[g * 12 + 6 + k] = __builtin_bit_cast(unsigned, whh4[(g * 6 + q4) * 6 + k]);
            }
            wx[g] = b4v[g * 6 + q4];
        }
#pragma unroll
        for (int k = 0; k < 6; ++k) wr[48 + k] = __builtin_bit_cast(unsigned, fcw[qf * 6 + k]);
        wx[4] = fcb[qf];
    }

    float* outb = out + (size_t)b * T_SZ * 6;

    for (int s2 = 0; s2 < T_SZ + 4; s2 += 2) {
#pragma unroll
        for (int half = 0; half < 2; ++half) {
            const int s   = s2 + half;
            const int cur = half;
            const int prv = half ^ 1;

            if (wid < 4) {
                // ---- L1: rebuild h1[s-1], then gates of h1[s] ----
                if (s >= 1 && s < T_SZ)
                    lstm_cell(g1ls[prv][0][u], g1ls[prv][1][u],
                              g1ls[prv][2][u], g1ls[prv][3][u], cP, hP);
                if (s < T_SZ) {
                    const int pk = pack_pair(hP);
                    float a0 = (half ? xv1 : xv0), a1 = 0.f, a2 = 0.f, a3 = 0.f;
#pragma unroll
                    for (int k8 = 0; k8 < 8; ++k8) {
                        const int hs0 = __builtin_amdgcn_readlane(pk, 8 * k8 + 0);
                        const int hs1 = __builtin_amdgcn_readlane(pk, 8 * k8 + 2);
                        const int hs2 = __builtin_amdgcn_readlane(pk, 8 * k8 + 4);
                        const int hs3 = __builtin_amdgcn_readlane(pk, 8 * k8 + 6);
                        a0 = fdot2f(as_h2(wr[4 * k8 + 0]), __builtin_bit_cast(h2, hs0), a0);
                        a1 = fdot2f(as_h2(wr[4 * k8 + 1]), __builtin_bit_cast(h2, hs1), a1);
                        a2 = fdot2f(as_h2(wr[4 * k8 + 2]), __builtin_bit_cast(h2, hs2), a2);
                        a3 = fdot2f(as_h2(wr[4 * k8 + 3]), __builtin_bit_cast(h2, hs3), a3);
                    }
                    g1ls[cur][wid][u] = (a0 + a1) + (a2 + a3);
                    const int tp = (s + 2 < T_SZ) ? (s + 2) : (T_SZ - 1);
                    const float xnew = xgb[(size_t)tp * 256];
                    if (half) xv1 = xnew; else xv0 = xnew;
                }
            } else if (wid < 8) {
                // ---- L2: rebuild h1[s-1] and h2[s-2], then gates of h2[s-1] -
                if (s >= 1 && s <= T_SZ) {
                    lstm_cell(g1ls[prv][0][u], g1ls[prv][1][u],
                              g1ls[prv][2][u], g1ls[prv][3][u], cP, hP);
                    if (s >= 2)
                        lstm_cell(g2ls[prv][0][u], g2ls[prv][1][u],
                                  g2ls[prv][2][u], g2ls[prv][3][u], cQ, hQ);
                    const int pkP = pack_pair(hP);
                    const int pkQ = pack_pair(hQ);
                    float a0 = wx[0], a1 = 0.f, a2 = 0.f, a3 = 0.f;
#pragma unroll
                    for (int k8 = 0; k8 < 8; ++k8) {
                        const int hs0 = __builtin_amdgcn_readlane(pkP, 8 * k8 + 0);
                        const int hs1 = __builtin_amdgcn_readlane(pkP, 8 * k8 + 2);
                        const int hs2 = __builtin_amdgcn_readlane(pkP, 8 * k8 + 4);
                        const int hs3 = __builtin_amdgcn_readlane(pkP, 8 * k8 + 6);
                        a0 = fdot2f(as_h2(wr[4 * k8 + 0]), __builtin_bit_cast(h2, hs0), a0);
                        a1 = fdot2f(as_h2(wr[4 * k8 + 1]), __builtin_bit_cast(h2, hs1), a1);
                        a2 = fdot2f(as_h2(wr[4 * k8 + 2]), __builtin_bit_cast(h2, hs2), a2);
                        a3 = fdot2f(as_h2(wr[4 * k8 + 3]), __builtin_bit_cast(h2, hs3), a3);
                    }
#pragma unroll
                    for (int k8 = 0; k8 < 8; ++k8) {
                        const int hs0 = __builtin_amdgcn_readlane(pkQ, 8 * k8 + 0);
                        const int hs1 = __builtin_amdgcn_readlane(pkQ, 8 * k8 + 2);
                        const int hs2 = __builtin_amdgcn_readlane(pkQ, 8 * k8 + 4);
                        const int hs3 = __builtin_amdgcn_readlane(pkQ, 8 * k8 + 6);
                        a0 = fdot2f(as_h2(wr[32 + 4 * k8 + 0]), __builtin_bit_cast(h2, hs0), a0);
                        a1 = fdot2f(as_h2(wr[32 + 4 * k8 + 1]), __builtin_bit_cast(h2, hs1), a1);
                        a2 = fdot2f(as_h2(wr[32 + 4 * k8 + 2]), __builtin_bit_cast(h2, hs2), a2);
                        a3 = fdot2f(as_h2(wr[32 + 4 * k8 + 3]), __builtin_bit_cast(h2, hs3), a3);
                    }
                    g2ls[cur][wid - 4][u] = (a0 + a1) + (a2 + a3);
                }
            } else if (wid == 8) {
                // ---- L3 at t3 = s-2: rebuild h2[s-2], in-reg broadcast -----
                if (s >= 2 && s <= T_SZ + 1) {
                    lstm_cell(g2ls[prv][0][u], g2ls[prv][1][u],
                              g2ls[prv][2][u], g2ls[prv][3][u], cP, hP);
                    const int hb = __builtin_bit_cast(int, hP);
                    float d0 = wx[6], d1 = 0.f, d2 = 0.f, d3 = 0.f;
#pragma unroll
                    for (int j = 0; j < 64; j += 4) {
                        d0 = fmaf(as_f(wr[j + 0]), as_f(__builtin_amdgcn_readlane(hb, j + 0)), d0);
                        d1 = fmaf(as_f(wr[j + 1]), as_f(__builtin_amdgcn_readlane(hb, j + 1)), d1);
                        d2 = fmaf(as_f(wr[j + 2]), as_f(__builtin_amdgcn_readlane(hb, j + 2)), d2);
                        d3 = fmaf(as_f(wr[j + 3]), as_f(__builtin_amdgcn_readlane(hb, j + 3)), d3);
                    }
                    // recurrence: h3[t3-1] from own lanes 0-5 (hQ)
                    const int h3b = __builtin_bit_cast(int, hQ);
                    d0 = fmaf(wx[0], as_f(__builtin_amdgcn_readlane(h3b, 0)), d0);
                    d1 = fmaf(wx[1], as_f(__builtin_amdgcn_readlane(h3b, 1)), d1);
                    d2 = fmaf(wx[2], as_f(__builtin_amdgcn_readlane(h3b, 2)), d2);
                    d3 = fmaf(wx[3], as_f(__builtin_amdgcn_readlane(h3b, 3)), d3);
                    d0 = fmaf(wx[4], as_f(__builtin_amdgcn_readlane(h3b, 4)), d0);
                    d1 = fmaf(wx[5], as_f(__builtin_amdgcn_readlane(h3b, 5)), d1);
                    const float p = (d0 + d1) + (d2 + d3);
                    const int pb = __builtin_bit_cast(int, p);
                    const float p0 = as_f(__builtin_amdgcn_ds_bpermute(uu4, pb));
                    const float p1 = as_f(__builtin_amdgcn_ds_bpermute(uu4 + 24, pb));
                    const float p2 = as_f(__builtin_amdgcn_ds_bpermute(uu4 + 48, pb));
                    const float p3 = as_f(__builtin_amdgcn_ds_bpermute(uu4 + 72, pb));
                    if (u < 6) {
                        lstm_cell(p0, p1, p2, p3, cQ, hQ);
                        h3f[cur][u] = hQ;
                    }
                }
            } else {
                // ---- L4 at t4 = s-3; FC writes out[s-4] --------------------
                const int t4 = s - 3;
                const int h4b = __builtin_bit_cast(int, hQ);
                float v4[6];
#pragma unroll
                for (int k = 0; k < 6; ++k)
                    v4[k] = as_f(__builtin_amdgcn_readlane(h4b, k));
                const int tout = t4 - 1;
                if (tout >= 0 && tout < T_SZ && u >= 6 && u < 12) {
                    float o = wx[4];
#pragma unroll
                    for (int k = 0; k < 6; ++k) o = fmaf(as_f(wr[48 + k]), v4[k], o);
                    outb[(size_t)tout * 6 + (u - 6)] = o;
                }
                if (t4 >= 0 && t4 < T_SZ) {
                    float v[12];
#pragma unroll
                    for (int k = 0; k < 6; ++k) v[k] = h3f[prv][k];   // h3[t4]
#pragma unroll
                    for (int k = 0; k < 6; ++k) v[6 + k] = v4[k];     // h4[t4-1]
                    float pg[4];
#pragma unroll
                    for (int g = 0; g < 4; ++g) {
                        float a = wx[g];
#pragma unroll
                        for (int k = 0; k < 12; ++k) a = fmaf(as_f(wr[g * 12 + k]), v[k], a);
                        pg[g] = a;
                    }
                    if (u < 6) lstm_cell(pg[0], pg[1], pg[2], pg[3], cQ, hQ);
                }
            }

            asm volatile("s_waitcnt lgkmcnt(0)" ::: "memory");
            __builtin_amdgcn_s_barrier();
            asm volatile("" ::: "memory");
        }
    }
}

extern "C" void kernel_launch(void* const* d_in, const int* in_sizes, int n_in,
                              void* d_out, int out_size, void* d_ws, size_t ws_size,
                              hipStream_t stream) {
    const float* x      = (const float*)d_in[0];
    const float* w1_ih0 = (const float*)d_in[1];
    const float* w1_hh0 = (const float*)d_in[2];
    const float* b1_0   = (const float*)d_in[3];
    const float* w1_ih1 = (const float*)d_in[4];
    const float* w1_hh1 = (const float*)d_in[5];
    const float* b1_1   = (const float*)d_in[6];
    const float* w2_ih0 = (const float*)d_in[7];
    const float* w2_hh0 = (const float*)d_in[8];
    const float* b2_0   = (const float*)d_in[9];
    const float* w2_ih1 = (const float*)d_in[10];
    const float* w2_hh1 = (const float*)d_in[11];
    const float* b2_1   = (const float*)d_in[12];
    const float* fc_w   = (const float*)d_in[13];
    const float* fc_b   = (const float*)d_in[14];
    float* out = (float*)d_out;

    const int M = M_SZ;
    float* xg = (float*)d_ws;                           // M*256 f32
    _Float16* w16a = (_Float16*)(xg + (size_t)M * 256); // 256*512 f16

    f32_to_f16<<<(256 * 512 + 255) / 256, 256, 0, stream>>>(w1_ih0, w16a, 256 * 512);

    // L1 input projection (x known upfront): 512 -> 256 gates, bias folded
    gemm_mfma<512><<<M / 64, 256, 0, stream>>>(x, w16a, b1_0, xg);

    // everything recurrent, pipelined in one kernel, one barrier per step
    lstm_fused<<<B_SZ, 640, 0, stream>>>(xg, w1_hh0,
                                         w1_ih1, w1_hh1, b1_1,
                                         w2_ih0, w2_hh0, b2_0,
                                         w2_ih1, w2_hh1, b2_1,
                                         fc_w, fc_b, out);
}

// Round 4
// 1153.950 us; speedup vs baseline: 1.7390x; 1.7390x over previous
//
#include <hip/hip_runtime.h>
#include <hip/hip_bf16.h>

// 4 stacked LSTM layers (512->64, 64->64, 64->6, 6->6) + FC(6->6).
// B=64, T=1024, M = B*T = 65536.
//
// R9: cross-BLOCK pipeline. R7/R8 showed that fusing layers into one block
//     couples all waves through the block barrier and stretches the step to
//     the worst serial chain (3419 / 4186 cy vs R6's proven 1062 cy). Here
//     each layer keeps its exact R6 step structure in its OWN blocks, and
//     layers overlap via chunked producer->consumer handoff through global
//     memory with AGENT-scope release/acquire flags (cross-XCD safe; acquire
//     also invalidates stale L2 across graph replays):
//       role 0 (blocks   0- 63, 4 waves): L1 scan, stores h1 as packed f16
//               pairs, publishes progress every 16 steps.
//       role 1 (blocks  64-127, 4 waves): L2 scan with ON-THE-FLY input
//               projection (64 fdot2/lane) -- deletes gemm_mfma<64>.
//       role 2 (blocks 128-191, 1 wave): L3+L4+FC scan66-style, with
//               ON-THE-FLY 64->24 projection in lanes 24-47 -- deletes
//               gemm_naive.
//     Grid 192 <= 256 CUs, VGPR ~90-150, LDS 2KB -> all blocks co-resident.
//     Consumers chunk-wait (relaxed spin + s_sleep, then acquire) so the
//     wall time ~= slowest single scan + ~32-step skew per boundary.

#define B_SZ 64
#define T_SZ 1024
#define M_SZ (B_SZ * T_SZ)
#define CHUNK 16
#define PF 4

typedef _Float16 h2   __attribute__((ext_vector_type(2)));
typedef _Float16 h8   __attribute__((ext_vector_type(8)));
typedef float    f32x4 __attribute__((ext_vector_type(4)));

__device__ __forceinline__ float sigm_f(float x) {
    return 1.0f / (1.0f + __expf(-x));
}
__device__ __forceinline__ float tanh_f(float x) {
    return 2.0f / (1.0f + __expf(-2.0f * x)) - 1.0f;
}

__device__ __forceinline__ float fdot2f(h2 a, h2 b, float c) {
#if __has_builtin(__builtin_amdgcn_fdot2)
    return __builtin_amdgcn_fdot2(a, b, c, false);
#else
    return c + (float)a.x * (float)b.x + (float)a.y * (float)b.y;
#endif
}

__device__ __forceinline__ unsigned pack_h2(float a, float b) {
    h2 p; p.x = (_Float16)a; p.y = (_Float16)b;
    return __builtin_bit_cast(unsigned, p);
}
__device__ __forceinline__ h2 as_h2(unsigned x) { return __builtin_bit_cast(h2, x); }
__device__ __forceinline__ float as_f(unsigned x) { return __builtin_bit_cast(float, x); }
__device__ __forceinline__ float as_f(int x) { return __builtin_bit_cast(float, x); }

// even lane 2i ends with {h[2i], h[2i+1]} packed as 2xf16
__device__ __forceinline__ int pack_pair(float h) {
    const _Float16 hf = (_Float16)h;
    const int hb = (int)__builtin_bit_cast(unsigned short, hf);
    const int nb = __builtin_amdgcn_update_dpp(0, hb, 0xB1, 0xF, 0xF, true);
    return hb | (nb << 16);
}

__device__ __forceinline__ void lstm_cell(float p0, float p1, float p2, float p3,
                                          float& c, float& h) {
    const float iv = sigm_f(p0);
    const float fv = sigm_f(p1);
    const float gv = tanh_f(p2);
    const float ov = sigm_f(p3);
    c = fv * c + iv * gv;
    h = ov * tanh_f(c);
}

__device__ __forceinline__ void wait_flag(const unsigned* f, unsigned need) {
    while (__hip_atomic_load(f, __ATOMIC_RELAXED, __HIP_MEMORY_SCOPE_AGENT) < need)
        __builtin_amdgcn_s_sleep(2);
    (void)__hip_atomic_load(f, __ATOMIC_ACQUIRE, __HIP_MEMORY_SCOPE_AGENT);
}
__device__ __forceinline__ void publish_flag(unsigned* f, unsigned v) {
    __hip_atomic_store(f, v, __ATOMIC_RELEASE, __HIP_MEMORY_SCOPE_AGENT);
}

// ---------------- fp32 -> f16 converter (for W_ih weights) ------------------
__global__ __launch_bounds__(256) void f32_to_f16(const float* __restrict__ src,
                                                  _Float16* __restrict__ dst, int n) {
    const int i = blockIdx.x * 256 + threadIdx.x;
    if (i < n) dst[i] = (_Float16)src[i];
}

__global__ void init_flags(unsigned* f) { f[threadIdx.x] = 0; }

// ---------------- MFMA input-projection GEMM (layer 1 only) -----------------
template <int K>
__global__ __launch_bounds__(256) void gemm_mfma(const float* __restrict__ X,
                                                 const _Float16* __restrict__ W16,
                                                 const float* __restrict__ bias,
                                                 float* __restrict__ out) {
    const int m0   = blockIdx.x * 64;
    const int tid  = threadIdx.x;
    const int wv   = tid >> 6;
    const int lane = tid & 63;
    const int lh   = lane & 15;
    const int quad = lane >> 4;
    const int n0   = wv * 64;

    __shared__ __align__(16) _Float16 Als[64 * 32];

    f32x4 acc[4][4];
#pragma unroll
    for (int nt = 0; nt < 4; ++nt) {
        const float bg = bias[n0 + nt * 16 + lh];
#pragma unroll
        for (int mt = 0; mt < 4; ++mt) {
            acc[mt][nt].x = bg; acc[mt][nt].y = bg;
            acc[mt][nt].z = bg; acc[mt][nt].w = bg;
        }
    }

    const int srow = tid >> 2;
    const int sk8  = tid & 3;
    const int sdst = srow * 32 + ((sk8 ^ (srow & 3)) * 8);

    for (int k0 = 0; k0 < K; k0 += 32) {
        const float* xr = X + (size_t)(m0 + srow) * K + k0 + sk8 * 8;
        const float4 a4 = ((const float4*)xr)[0];
        const float4 b4 = ((const float4*)xr)[1];
        h8 bfrag[4];
#pragma unroll
        for (int nt = 0; nt < 4; ++nt) {
            bfrag[nt] = *(const h8*)&W16[(size_t)(n0 + nt * 16 + lh) * K + k0 + quad * 8];
        }
        h8 hv;
        hv[0] = (_Float16)a4.x; hv[1] = (_Float16)a4.y;
        hv[2] = (_Float16)a4.z; hv[3] = (_Float16)a4.w;
        hv[4] = (_Float16)b4.x; hv[5] = (_Float16)b4.y;
        hv[6] = (_Float16)b4.z; hv[7] = (_Float16)b4.w;

        __syncthreads();
        *(h8*)&Als[sdst] = hv;
        __syncthreads();

        h8 afrag[4];
#pragma unroll
        for (int mt = 0; mt < 4; ++mt) {
            const int row = mt * 16 + lh;
            afrag[mt] = *(const h8*)&Als[row * 32 + ((quad ^ (row & 3)) * 8)];
        }
#pragma unroll
        for (int mt = 0; mt < 4; ++mt)
#pragma unroll
            for (int nt = 0; nt < 4; ++nt)
                acc[mt][nt] = __builtin_amdgcn_mfma_f32_16x16x32_f16(
                    afrag[mt], bfrag[nt], acc[mt][nt], 0, 0, 0);
    }

#pragma unroll
    for (int mt = 0; mt < 4; ++mt)
#pragma unroll
        for (int nt = 0; nt < 4; ++nt)
#pragma unroll
            for (int r = 0; r < 4; ++r)
                out[(size_t)(m0 + mt * 16 + quad * 4 + r) * 256 + n0 + nt * 16 + lh] =
                    acc[mt][nt][r];
}

// ---------------- pipelined scan, one role per block ------------------------
__global__ __launch_bounds__(256, 1) void lstm_pipe(
        const float* __restrict__ xg,     // [B,T,256] L1 gates (bias folded)
        const float* __restrict__ whh1,   // [256][64]
        const float* __restrict__ wih2,   // [256][64]
        const float* __restrict__ whh2,   // [256][64]
        const float* __restrict__ b2v,    // [256]
        const float* __restrict__ wih3,   // [24][64]
        const float* __restrict__ whh3,   // [24][6]
        const float* __restrict__ b3v,    // [24]
        const float* __restrict__ wih4,   // [24][6]
        const float* __restrict__ whh4,   // [24][6]
        const float* __restrict__ b4v,    // [24]
        const float* __restrict__ fcw,    // [6][6]
        const float* __restrict__ fcb,    // [6]
        unsigned* __restrict__ h1p,       // [B,T,32] packed f16 pairs of h1
        float* __restrict__ h2g,          // [B,T,64] f32 h2
        unsigned* __restrict__ flags,     // [0:64) role0->1, [64:128) role1->2
        float* __restrict__ out) {        // [B,T,6]
    const int role = blockIdx.x >> 6;
    const int b    = blockIdx.x & 63;
    const int tid  = threadIdx.x;
    const int g    = tid >> 6;
    const int u    = tid & 63;

    __shared__ __align__(16) float pls[2][4][64];

    if (role == 0) {
        // =================== L1: proven scan64_coop step =====================
        unsigned w[32];
        {
            const float* wr = whh1 + (size_t)(g * 64 + u) * 64;
#pragma unroll
            for (int k2 = 0; k2 < 32; ++k2) w[k2] = pack_h2(wr[2 * k2], wr[2 * k2 + 1]);
        }
        const float* xgb = xg + (size_t)b * T_SZ * 256 + g * 64 + u;
        float xv[4];
#pragma unroll
        for (int s = 0; s < 4; ++s) xv[s] = xgb[(size_t)s * 256];
        unsigned* hp = h1p + (size_t)b * T_SZ * 32;
        unsigned* fl = flags + b;
        float c = 0.0f, h = 0.0f;
        int pkS = 0;

        for (int t4 = 0; t4 < T_SZ; t4 += 4) {
#pragma unroll
            for (int s = 0; s < 4; ++s) {
                const int t = t4 + s;
                float a0 = xv[s], a1 = 0.f, a2 = 0.f, a3 = 0.f;
#pragma unroll
                for (int k8 = 0; k8 < 8; ++k8) {
                    const int hs0 = __builtin_amdgcn_readlane(pkS, 8 * k8 + 0);
                    const int hs1 = __builtin_amdgcn_readlane(pkS, 8 * k8 + 2);
                    const int hs2 = __builtin_amdgcn_readlane(pkS, 8 * k8 + 4);
                    const int hs3 = __builtin_amdgcn_readlane(pkS, 8 * k8 + 6);
                    a0 = fdot2f(as_h2(w[4 * k8 + 0]), __builtin_bit_cast(h2, hs0), a0);
                    a1 = fdot2f(as_h2(w[4 * k8 + 1]), __builtin_bit_cast(h2, hs1), a1);
                    a2 = fdot2f(as_h2(w[4 * k8 + 2]), __builtin_bit_cast(h2, hs2), a2);
                    a3 = fdot2f(as_h2(w[4 * k8 + 3]), __builtin_bit_cast(h2, hs3), a3);
                }
                pls[t & 1][g][u] = (a0 + a1) + (a2 + a3);
                asm volatile("s_waitcnt lgkmcnt(0)" ::: "memory");
                __builtin_amdgcn_s_barrier();
                asm volatile("" ::: "memory");
                const float p0 = pls[t & 1][0][u];
                const float p1 = pls[t & 1][1][u];
                const float p2 = pls[t & 1][2][u];
                const float p3 = pls[t & 1][3][u];
                const int tp = (t + 4 < T_SZ) ? (t + 4) : (T_SZ - 1);
                xv[s] = xgb[(size_t)tp * 256];
                lstm_cell(p0, p1, p2, p3, c, h);
                pkS = pack_pair(h);
                if (g == 0) {
                    if (!(u & 1)) hp[(size_t)t * 32 + (u >> 1)] = (unsigned)pkS;
                    if (u == 0 && ((t & (CHUNK - 1)) == (CHUNK - 1)))
                        publish_flag(fl, (unsigned)(t + 1));
                }
            }
        }
    } else if (role == 1) {
        // ======= L2: same step + on-the-fly input projection (64 fdot2) ======
        unsigned wi[32], wh[32];
        {
            const float* a = wih2 + (size_t)(g * 64 + u) * 64;
            const float* bb = whh2 + (size_t)(g * 64 + u) * 64;
#pragma unroll
            for (int k2 = 0; k2 < 32; ++k2) {
                wi[k2] = pack_h2(a[2 * k2], a[2 * k2 + 1]);
                wh[k2] = pack_h2(bb[2 * k2], bb[2 * k2 + 1]);
            }
        }
        const float bias = b2v[g * 64 + u];
        const unsigned* hp = h1p + (size_t)b * T_SZ * 32;
        float* h2b = h2g + (size_t)b * T_SZ * 64;
        unsigned* flin  = flags + b;
        unsigned* flout = flags + 64 + b;

        wait_flag(flin, (T_SZ < CHUNK + PF) ? T_SZ : (CHUNK + PF));
        unsigned hv[4];
#pragma unroll
        for (int s = 0; s < 4; ++s) hv[s] = hp[(size_t)s * 32 + (u & 31)];
        float c = 0.0f, h = 0.0f;
        int pkQ = 0;

        for (int t4 = 0; t4 < T_SZ; t4 += 4) {
            if (t4 && (t4 & (CHUNK - 1)) == 0) {
                unsigned need = t4 + CHUNK + PF;
                if (need > T_SZ) need = T_SZ;
                wait_flag(flin, need);
            }
#pragma unroll
            for (int s = 0; s < 4; ++s) {
                const int t = t4 + s;
                const int hw = (int)hv[s];
                float a0 = bias, a1 = 0.f, a2 = 0.f, a3 = 0.f;
                float d0 = 0.f, d1 = 0.f, d2 = 0.f, d3 = 0.f;
#pragma unroll
                for (int k8 = 0; k8 < 8; ++k8) {
                    const int j = 4 * k8;
                    const int i0 = __builtin_amdgcn_readlane(hw, j + 0);
                    const int i1 = __builtin_amdgcn_readlane(hw, j + 1);
                    const int i2 = __builtin_amdgcn_readlane(hw, j + 2);
                    const int i3 = __builtin_amdgcn_readlane(hw, j + 3);
                    a0 = fdot2f(as_h2(wi[j + 0]), __builtin_bit_cast(h2, i0), a0);
                    a1 = fdot2f(as_h2(wi[j + 1]), __builtin_bit_cast(h2, i1), a1);
                    a2 = fdot2f(as_h2(wi[j + 2]), __builtin_bit_cast(h2, i2), a2);
                    a3 = fdot2f(as_h2(wi[j + 3]), __builtin_bit_cast(h2, i3), a3);
                    const int q0 = __builtin_amdgcn_readlane(pkQ, 2 * j + 0);
                    const int q1 = __builtin_amdgcn_readlane(pkQ, 2 * j + 2);
                    const int q2 = __builtin_amdgcn_readlane(pkQ, 2 * j + 4);
                    const int q3 = __builtin_amdgcn_readlane(pkQ, 2 * j + 6);
                    d0 = fdot2f(as_h2(wh[j + 0]), __builtin_bit_cast(h2, q0), d0);
                    d1 = fdot2f(as_h2(wh[j + 1]), __builtin_bit_cast(h2, q1), d1);
                    d2 = fdot2f(as_h2(wh[j + 2]), __builtin_bit_cast(h2, q2), d2);
                    d3 = fdot2f(as_h2(wh[j + 3]), __builtin_bit_cast(h2, q3), d3);
                }
                pls[t & 1][g][u] = ((a0 + a1) + (a2 + a3)) + ((d0 + d1) + (d2 + d3));
                asm volatile("s_waitcnt lgkmcnt(0)" ::: "memory");
                __builtin_amdgcn_s_barrier();
                asm volatile("" ::: "memory");
                const float p0 = pls[t & 1][0][u];
                const float p1 = pls[t & 1][1][u];
                const float p2 = pls[t & 1][2][u];
                const float p3 = pls[t & 1][3][u];
                const int tp = (t + 4 < T_SZ) ? (t + 4) : (T_SZ - 1);
                hv[s] = hp[(size_t)tp * 32 + (u & 31)];
                lstm_cell(p0, p1, p2, p3, c, h);
                pkQ = pack_pair(h);
                if (g == 0) {
                    h2b[(size_t)t * 64 + u] = h;
                    if (u == 0 && ((t & (CHUNK - 1)) == (CHUNK - 1)))
                        publish_flag(flout, (unsigned)(t + 1));
                }
            }
        }
    } else {
        // ========== L3 + L4 + FC, one wave, with on-the-fly projection =======
        if (tid >= 64) return;
        float pw[64];
#pragma unroll
        for (int i = 0; i < 64; ++i) pw[i] = 0.0f;
        float pb = 0.0f;

        if (u < 6) {
#pragma unroll
            for (int g4 = 0; g4 < 4; ++g4)
#pragma unroll
                for (int k = 0; k < 6; ++k)
                    pw[g4 * 6 + k] = whh3[(g4 * 6 + u) * 6 + k];
        } else if (u < 12) {
            const int q = u - 6;
#pragma unroll
            for (int g4 = 0; g4 < 4; ++g4) {
#pragma unroll
                for (int k = 0; k < 6; ++k) {
                    pw[g4 * 6 + k]      = wih4[(g4 * 6 + q) * 6 + k];
                    pw[24 + g4 * 6 + k] = whh4[(g4 * 6 + q) * 6 + k];
                }
                pw[48 + g4] = b4v[g4 * 6 + q];
            }
        } else if (u < 18) {
            const int q = u - 12;
#pragma unroll
            for (int k = 0; k < 6; ++k) pw[52 + k] = fcw[q * 6 + k];
            pb = fcb[q];
        } else if (u >= 24 && u < 48) {
            const int q = u - 24;
#pragma unroll
            for (int j = 0; j < 64; ++j) pw[j] = wih3[(size_t)q * 64 + j];
            pb = b3v[q];
        }

        const float* h2b = h2g + (size_t)b * T_SZ * 64;
        unsigned* flin = flags + 64 + b;
        float* outb = out + (size_t)b * T_SZ * 6;

        wait_flag(flin, (T_SZ < CHUNK + PF) ? T_SZ : (CHUNK + PF));
        float hv[4];
#pragma unroll
        for (int s = 0; s < 4; ++s) hv[s] = h2b[(size_t)s * 64 + u];
        float c = 0.0f, h = 0.0f;
        const int bpa = 96 + (u % 6) * 4;   // byte lane-addr of lane 24 + u%6

        for (int t4 = 0; t4 < T_SZ + 4; t4 += 4) {
            if (t4 && t4 < T_SZ && (t4 & (CHUNK - 1)) == 0) {
                unsigned need = t4 + CHUNK + PF;
                if (need > T_SZ) need = T_SZ;
                wait_flag(flin, need);
            }
#pragma unroll
            for (int s = 0; s < 4; ++s) {
                const int tt = t4 + s;
                const int hb = __builtin_bit_cast(int, h);
                float v3[6], v4[6];
#pragma unroll
                for (int k = 0; k < 6; ++k) v3[k] = as_f(__builtin_amdgcn_readlane(hb, k));
#pragma unroll
                for (int k = 0; k < 6; ++k) v4[k] = as_f(__builtin_amdgcn_readlane(hb, 6 + k));

                // FC: out[tt-2] from h4[tt-2]
                if (tt >= 2 && tt < T_SZ + 2 && u >= 12 && u < 18) {
                    float o = pb;
#pragma unroll
                    for (int k = 0; k < 6; ++k) o = fmaf(pw[52 + k], v4[k], o);
                    outb[(size_t)(tt - 2) * 6 + (u - 12)] = o;
                }
                // L4 cell: h4[tt-1] from h3[tt-1], h4[tt-2]
                if (tt >= 1 && tt <= T_SZ && u >= 6 && u < 12) {
                    float pg0 = pw[48], pg1 = pw[49], pg2 = pw[50], pg3 = pw[51];
#pragma unroll
                    for (int k = 0; k < 6; ++k) {
                        pg0 = fmaf(pw[0 * 6 + k], v3[k], pg0);
                        pg1 = fmaf(pw[1 * 6 + k], v3[k], pg1);
                        pg2 = fmaf(pw[2 * 6 + k], v3[k], pg2);
                        pg3 = fmaf(pw[3 * 6 + k], v3[k], pg3);
                        pg0 = fmaf(pw[24 + 0 * 6 + k], v4[k], pg0);
                        pg1 = fmaf(pw[24 + 1 * 6 + k], v4[k], pg1);
                        pg2 = fmaf(pw[24 + 2 * 6 + k], v4[k], pg2);
                        pg3 = fmaf(pw[24 + 3 * 6 + k], v4[k], pg3);
                    }
                    lstm_cell(pg0, pg1, pg2, pg3, c, h);
                }
                // projection: proj[q] = b3[q] + wih3[q] . h2[tt]  (lanes 24-47)
                float pr = 0.0f;
                if (tt < T_SZ) {
                    const int hw = __builtin_bit_cast(int, hv[s]);
                    float d0 = pb, d1 = 0.f, d2 = 0.f, d3 = 0.f;
#pragma unroll
                    for (int j = 0; j < 64; j += 4) {
                        d0 = fmaf(pw[j + 0], as_f(__builtin_amdgcn_readlane(hw, j + 0)), d0);
                        d1 = fmaf(pw[j + 1], as_f(__builtin_amdgcn_readlane(hw, j + 1)), d1);
                        d2 = fmaf(pw[j + 2], as_f(__builtin_amdgcn_readlane(hw, j + 2)), d2);
                        d3 = fmaf(pw[j + 3], as_f(__builtin_amdgcn_readlane(hw, j + 3)), d3);
                    }
                    pr = (d0 + d1) + (d2 + d3);
                }
                // exchange proj -> L3 lanes (whole-wave bpermute)
                const int prb = __builtin_bit_cast(int, pr);
                float pr4[4];
#pragma unroll
                for (int g4 = 0; g4 < 4; ++g4)
                    pr4[g4] = as_f(__builtin_amdgcn_ds_bpermute(bpa + g4 * 24, prb));
                // prefetch h2[tt+4]
                if (tt < T_SZ) {
                    const int tp = (tt + 4 < T_SZ) ? (tt + 4) : (T_SZ - 1);
                    hv[s] = h2b[(size_t)tp * 64 + u];
                }
                // L3 cell: h3[tt] from h2[tt], h3[tt-1]
                if (tt < T_SZ && u < 6) {
                    float q0 = pr4[0], q1 = pr4[1], q2 = pr4[2], q3 = pr4[3];
#pragma unroll
                    for (int k = 0; k < 6; ++k) {
                        q0 = fmaf(pw[0 * 6 + k], v3[k], q0);
                        q1 = fmaf(pw[1 * 6 + k], v3[k], q1);
                        q2 = fmaf(pw[2 * 6 + k], v3[k], q2);
                        q3 = fmaf(pw[3 * 6 + k], v3[k], q3);
                    }
                    lstm_cell(q0, q1, q2, q3, c, h);
                }
            }
        }
    }
}

extern "C" void kernel_launch(void* const* d_in, const int* in_sizes, int n_in,
                              void* d_out, int out_size, void* d_ws, size_t ws_size,
                              hipStream_t stream) {
    const float* x      = (const float*)d_in[0];
    const float* w1_ih0 = (const float*)d_in[1];
    const float* w1_hh0 = (const float*)d_in[2];
    const float* b1_0   = (const float*)d_in[3];
    const float* w1_ih1 = (const float*)d_in[4];
    const float* w1_hh1 = (const float*)d_in[5];
    const float* b1_1   = (const float*)d_in[6];
    const float* w2_ih0 = (const float*)d_in[7];
    const float* w2_hh0 = (const float*)d_in[8];
    const float* b2_0   = (const float*)d_in[9];
    const float* w2_ih1 = (const float*)d_in[10];
    const float* w2_hh1 = (const float*)d_in[11];
    const float* b2_1   = (const float*)d_in[12];
    const float* fc_w   = (const float*)d_in[13];
    const float* fc_b   = (const float*)d_in[14];
    float* out = (float*)d_out;

    const int M = M_SZ;
    float*    xg    = (float*)d_ws;                        // M*256 f32
    unsigned* h1p   = (unsigned*)(xg + (size_t)M * 256);   // M*32  u32
    float*    h2g   = (float*)(h1p + (size_t)M * 32);      // M*64  f32
    _Float16* w16a  = (_Float16*)(h2g + (size_t)M * 64);   // 256*512 f16
    unsigned* flags = (unsigned*)(w16a + 256 * 512);       // 128 u32

    init_flags<<<1, 128, 0, stream>>>(flags);
    f32_to_f16<<<(256 * 512 + 255) / 256, 256, 0, stream>>>(w1_ih0, w16a, 256 * 512);

    // L1 input projection (x known upfront): 512 -> 256 gates, bias folded
    gemm_mfma<512><<<M / 64, 256, 0, stream>>>(x, w16a, b1_0, xg);

    // all recurrent layers, pipelined across blocks
    lstm_pipe<<<192, 256, 0, stream>>>(xg, w1_hh0,
                                       w1_ih1, w1_hh1, b1_1,
                                       w2_ih0, w2_hh0, b2_0,
                                       w2_ih1, w2_hh1, b2_1,
                                       fc_w, fc_b,
                                       h1p, h2g, flags, out);
}